// Round 9
// baseline (401.972 us; speedup 1.0000x reference)
//
#include <hip/hip_runtime.h>

// ============================================================================
// R9 MEASUREMENT ROUND: R4's verified 36.7us pipeline with zq/fattn/proj
// bodies repeated x24 inside their dispatches (idempotent), so each kernel
// exceeds the ~40us harness fills and surfaces in rocprof's top-5 with its
// own counters.  Per-kernel time = dur_us / 24.  pool left un-inflated.
// ============================================================================

// Problem constants
#define NB 16
#define NC 64
#define NM 6
#define ND 192
#define NHEADS 8
#define NCH 64
#define NINNER 512
#define PLANE 6144             // 64*96 floats per (b,c) plane
#define XB (NC*PLANE)          // 393216 floats of x per batch
#define NKEY 768               // unique keys per head (dup-8 collapses in softmax)
#define NCHUNK 8
#define CK 96                  // keys per chunk (8*96 = 768)
#define KP 68                  // k/q row pitch
#define SP 100                 // s row pitch

#define REPK 24                // diagnostic repeat factor

// ---------------- Kernel A: pool (verbatim, UN-inflated) ----------------
__global__ __launch_bounds__(256) void pool_kernel(const float* __restrict__ x,
                                                   float* __restrict__ xmean) {
    int bc = blockIdx.x;
    const float4* p = (const float4*)(x + (size_t)bc * PLANE);
    int tid = threadIdx.x;
    float acc[6] = {0.f,0.f,0.f,0.f,0.f,0.f};
    #pragma unroll
    for (int k = 0; k < 6; ++k) {
        int idx4 = tid + k * 256;
        int hh = idx4 / 24;
        int w4 = idx4 - hh * 24;
        int j = (hh >> 5) * 3 + (w4 >> 3);
        float4 v = p[idx4];
        acc[j] += v.x + v.y + v.z + v.w;
    }
    int lane = tid & 63, wave = tid >> 6;
    #pragma unroll
    for (int j = 0; j < 6; ++j) {
        float v = acc[j];
        for (int off = 32; off > 0; off >>= 1) v += __shfl_down(v, off, 64);
        acc[j] = v;
    }
    __shared__ float part[4][6];
    if (lane == 0) {
        #pragma unroll
        for (int j = 0; j < 6; ++j) part[wave][j] = acc[j];
    }
    __syncthreads();
    if (tid < 6) {
        float s = part[0][tid] + part[1][tid] + part[2][tid] + part[3][tid];
        xmean[bc * 6 + tid] = s * (1.0f / 1024.0f);
    }
}

// ---------------- Kernel B: zq (R4 verbatim body, x24) ----------------
__global__ __launch_bounds__(256) void zq_kernel(const float* __restrict__ z,
                                                 const float* __restrict__ conv_w,
                                                 const float* __restrict__ conv_b,
                                                 const float* __restrict__ wq,
                                                 const float* __restrict__ bq,
                                                 const float* __restrict__ xmean,
                                                 float* __restrict__ znew,
                                                 float* __restrict__ qr) {
    int blk = blockIdx.x;
    int cgrp = blk & 7, bm = blk >> 3;
    int b = bm / NM, m = bm - b * NM;
    int tid = threadIdx.x;
    __shared__ float xm[NC];
    __shared__ float zn[ND];
    __shared__ float qpart[3][64];
    #pragma unroll 1
    for (int rep = 0; rep < REPK; ++rep) {
        if (tid < NC) xm[tid] = xmean[(b * NC + tid) * NM + m];
        __syncthreads();
        if (tid < ND) {
            float a = conv_b[tid];
            const float* wr = conv_w + tid * NC;
            #pragma unroll 16
            for (int c = 0; c < NC; ++c) a += wr[c] * xm[c];
            float v = z[bm * ND + tid] + a;
            zn[tid] = v;
            if (cgrp == 0) znew[bm * ND + tid] = v;
        }
        __syncthreads();
        int colL = tid & 63, ks = tid >> 6;
        int col = cgrp * 64 + colL;
        float a = (ks == 0) ? bq[col] : 0.f;
        int d0 = ks * 48;
        #pragma unroll 8
        for (int d = d0; d < d0 + 48; ++d) a += zn[d] * wq[d * NINNER + col];
        if (ks > 0) qpart[ks - 1][colL] = a;
        __syncthreads();
        if (ks == 0) {
            float tot = a + qpart[0][colL] + qpart[1][colL] + qpart[2][colL];
            int t = m * 8 + cgrp;
            qr[b * (48 * 64) + t * 64 + colL] = tot;
        }
        __syncthreads();
    }
}

// ---------------- Kernel C: fattn (R4 verbatim body, x24) ----------------
__global__ __launch_bounds__(256, 4) void fattn_kernel(const float* __restrict__ x,
                                                       const float* __restrict__ qr,
                                                       float* __restrict__ po,
                                                       float* __restrict__ ps) {
    int blk = blockIdx.x;
    int chunk = blk & 7, bh = blk >> 3;
    int head = bh & 7, b = bh >> 3;
    int tid = threadIdx.x;
    __shared__ float k_lds[CK][KP];
    __shared__ float q_lds[NM][KP];
    __shared__ float s_lds[NM][SP];
    __shared__ float pvp[3][NM][NCH];
    const float* kbase = x + (size_t)b * XB + (size_t)(head * NKEY + chunk * CK) * NCH;
    #pragma unroll 1
    for (int rep = 0; rep < REPK; ++rep) {
        for (int i = tid; i < NM * NCH; i += 256) {
            int mi = i >> 6, ch = i & 63;
            q_lds[mi][ch] = qr[b * (48 * 64) + (head * NM + mi) * 64 + ch];
        }
        const float4* k4 = (const float4*)kbase;
        #pragma unroll
        for (int r = 0; r < 6; ++r) {
            int i = tid + r * 256;
            int row = i >> 4, c4 = i & 15;
            float4 v = k4[i];
            *(float4*)&k_lds[row][c4 * 4] = v;
        }
        __syncthreads();

        if (tid < 48) {
            int t = tid >> 1, mip = (tid & 1) * 3;
            float a[4][3];
            #pragma unroll
            for (int j = 0; j < 4; ++j) { a[j][0] = 0.f; a[j][1] = 0.f; a[j][2] = 0.f; }
            #pragma unroll 4
            for (int c = 0; c < 16; ++c) {
                float4 q0 = *(const float4*)&q_lds[mip + 0][c * 4];
                float4 q1 = *(const float4*)&q_lds[mip + 1][c * 4];
                float4 q2 = *(const float4*)&q_lds[mip + 2][c * 4];
                #pragma unroll
                for (int j = 0; j < 4; ++j) {
                    float4 kv = *(const float4*)&k_lds[t + 24 * j][c * 4];
                    a[j][0] += kv.x*q0.x + kv.y*q0.y + kv.z*q0.z + kv.w*q0.w;
                    a[j][1] += kv.x*q1.x + kv.y*q1.y + kv.z*q1.z + kv.w*q1.w;
                    a[j][2] += kv.x*q2.x + kv.y*q2.y + kv.z*q2.z + kv.w*q2.w;
                }
            }
            #pragma unroll
            for (int j = 0; j < 4; ++j) {
                s_lds[mip + 0][t + 24 * j] = __expf(a[j][0] * 0.125f);
                s_lds[mip + 1][t + 24 * j] = __expf(a[j][1] * 0.125f);
                s_lds[mip + 2][t + 24 * j] = __expf(a[j][2] * 0.125f);
            }
        }
        __syncthreads();

        int lane = tid & 63, wave = tid >> 6;
        #pragma unroll
        for (int rb = 0; rb < 2; ++rb) {
            int mi = rb * 4 + wave;
            if (mi < NM) {
                float v = s_lds[mi][lane] + ((lane < 32) ? s_lds[mi][64 + lane] : 0.f);
                for (int msk = 1; msk < 64; msk <<= 1) v += __shfl_xor(v, msk, 64);
                if (lane == 0) ps[blk * NM + mi] = v;
            }
        }

        float acc[NM] = {0.f,0.f,0.f,0.f,0.f,0.f};
        {
            int uq = tid >> 6, ch = tid & 63;
            int u0 = uq * 24;
            #pragma unroll
            for (int ub = 0; ub < 6; ++ub) {
                float4 s0 = *(const float4*)&s_lds[0][u0 + ub * 4];
                float4 s1 = *(const float4*)&s_lds[1][u0 + ub * 4];
                float4 s2 = *(const float4*)&s_lds[2][u0 + ub * 4];
                float4 s3 = *(const float4*)&s_lds[3][u0 + ub * 4];
                float4 s4 = *(const float4*)&s_lds[4][u0 + ub * 4];
                float4 s5 = *(const float4*)&s_lds[5][u0 + ub * 4];
                float kv0 = k_lds[u0 + ub * 4 + 0][ch];
                float kv1 = k_lds[u0 + ub * 4 + 1][ch];
                float kv2 = k_lds[u0 + ub * 4 + 2][ch];
                float kv3 = k_lds[u0 + ub * 4 + 3][ch];
                acc[0] += s0.x*kv0 + s0.y*kv1 + s0.z*kv2 + s0.w*kv3;
                acc[1] += s1.x*kv0 + s1.y*kv1 + s1.z*kv2 + s1.w*kv3;
                acc[2] += s2.x*kv0 + s2.y*kv1 + s2.z*kv2 + s2.w*kv3;
                acc[3] += s3.x*kv0 + s3.y*kv1 + s3.z*kv2 + s3.w*kv3;
                acc[4] += s4.x*kv0 + s4.y*kv1 + s4.z*kv2 + s4.w*kv3;
                acc[5] += s5.x*kv0 + s5.y*kv1 + s5.z*kv2 + s5.w*kv3;
            }
            if (uq > 0) {
                #pragma unroll
                for (int mo = 0; mo < NM; ++mo) pvp[uq - 1][mo][ch] = acc[mo];
            }
        }
        __syncthreads();
        if (tid < 64) {
            int ch = tid;
            #pragma unroll
            for (int mo = 0; mo < NM; ++mo) {
                float o = acc[mo] + pvp[0][mo][ch] + pvp[1][mo][ch] + pvp[2][mo][ch];
                po[(size_t)blk * (NM * NCH) + mo * NCH + ch] = o;
            }
        }
        __syncthreads();
    }
}

// ---------------- Kernel D: proj (R4 verbatim body, x24) ----------------
__global__ __launch_bounds__(256) void proj_kernel(const float* __restrict__ znew,
                                                   const float* __restrict__ po,
                                                   const float* __restrict__ ps,
                                                   const float* __restrict__ wo,
                                                   const float* __restrict__ bo,
                                                   float* __restrict__ out) {
    int blk = blockIdx.x;
    int cgrp = blk & 3, bm = blk >> 2;
    int b = bm / NM, m = bm - b * NM;
    int tid = threadIdx.x;
    __shared__ float orow[NINNER];
    __shared__ float part[3][48];
    #pragma unroll 1
    for (int rep = 0; rep < REPK; ++rep) {
        for (int i = tid; i < NINNER; i += 256) {
            int h = i >> 6, ch = i & 63;
            int base = (b * NHEADS + h) * NCHUNK;
            float num = 0.f, den = 0.f;
            #pragma unroll
            for (int c = 0; c < NCHUNK; ++c) {
                num += po[(size_t)(base + c) * (NM * NCH) + m * NCH + ch];
                den += ps[(base + c) * NM + m];
            }
            orow[i] = num / den;
        }
        __syncthreads();

        int ks = tid / 48;
        int colL = tid - ks * 48;
        float a = 0.f;
        int col = cgrp * 48 + ((tid < 192) ? colL : 0);
        if (tid < 192) {
            int i0 = ks * 128;
            #pragma unroll 8
            for (int i = i0; i < i0 + 128; ++i) a += orow[i] * wo[i * ND + col];
            if (ks > 0) part[ks - 1][colL] = a;
        }
        __syncthreads();
        if (tid < 48) {
            float tot = a + part[0][colL] + part[1][colL] + part[2][colL]
                      + bo[col] + znew[bm * ND + col];
            out[bm * ND + col] = tot;
        }
        __syncthreads();
    }
}

extern "C" void kernel_launch(void* const* d_in, const int* in_sizes, int n_in,
                              void* d_out, int out_size, void* d_ws, size_t ws_size,
                              hipStream_t stream) {
    const float* x      = (const float*)d_in[0];
    const float* z      = (const float*)d_in[1];
    const float* conv_w = (const float*)d_in[2];
    const float* conv_b = (const float*)d_in[3];
    const float* wq     = (const float*)d_in[4];
    const float* bq     = (const float*)d_in[5];
    const float* wo     = (const float*)d_in[6];
    const float* bo     = (const float*)d_in[7];
    float* out = (float*)d_out;

    float* ws    = (float*)d_ws;
    float* xmean = ws;              // 16*64*6          = 6144
    float* znew  = ws + 6144;       // 16*6*192         = 18432
    float* qr    = ws + 24576;      // 16*48*64         = 49152
    float* po    = ws + 73728;      // 1024*6*64        = 393216
    float* ps    = ws + 466944;     // 1024*6           = 6144

    pool_kernel<<<NB*NC, 256, 0, stream>>>(x, xmean);
    zq_kernel<<<NB*NM*8, 256, 0, stream>>>(z, conv_w, conv_b, wq, bq, xmean, znew, qr);
    fattn_kernel<<<NB*NHEADS*NCHUNK, 256, 0, stream>>>(x, qr, po, ps);
    proj_kernel<<<NB*NM*4, 256, 0, stream>>>(znew, po, ps, wo, bo, out);
}

// Round 10
// 32.274 us; speedup vs baseline: 12.4550x; 12.4550x over previous
//
#include <hip/hip_runtime.h>

// Problem constants
#define NB 16
#define NC 64
#define NM 6
#define ND 192
#define NHEADS 8
#define NCH 64
#define NINNER 512
#define PLANE 6144             // 64*96 floats per (b,c) plane
#define XB (NC*PLANE)          // 393216 floats of x per batch
#define NKEY 768               // unique keys per head (dup-8 collapses in softmax)
#define NCHUNK 8
#define CK 96                  // keys per chunk (8*96 = 768)
#define KP 68                  // k/q row pitch
#define SP 100                 // s row pitch

// ---------------- Kernel A: pool (verbatim R4) ----------------
__global__ __launch_bounds__(256) void pool_kernel(const float* __restrict__ x,
                                                   float* __restrict__ xmean) {
    int bc = blockIdx.x;
    const float4* p = (const float4*)(x + (size_t)bc * PLANE);
    int tid = threadIdx.x;
    float acc[6] = {0.f,0.f,0.f,0.f,0.f,0.f};
    #pragma unroll
    for (int k = 0; k < 6; ++k) {
        int idx4 = tid + k * 256;
        int hh = idx4 / 24;
        int w4 = idx4 - hh * 24;
        int j = (hh >> 5) * 3 + (w4 >> 3);
        float4 v = p[idx4];
        acc[j] += v.x + v.y + v.z + v.w;
    }
    int lane = tid & 63, wave = tid >> 6;
    #pragma unroll
    for (int j = 0; j < 6; ++j) {
        float v = acc[j];
        for (int off = 32; off > 0; off >>= 1) v += __shfl_down(v, off, 64);
        acc[j] = v;
    }
    __shared__ float part[4][6];
    if (lane == 0) {
        #pragma unroll
        for (int j = 0; j < 6; ++j) part[wave][j] = acc[j];
    }
    __syncthreads();
    if (tid < 6) {
        float s = part[0][tid] + part[1][tid] + part[2][tid] + part[3][tid];
        xmean[bc * 6 + tid] = s * (1.0f / 1024.0f);
    }
}

// ---------------- Kernel B: zq v3 — latency-chain diet ----------------
// grid = NB*NM*8 = 768 blocks, 256 threads (proven grid shape).
// conv_w read as float4 (16 loads/thread vs 64, 4x ILP); q-dot fully
// unrolled so the compiler pipelines ~16 outstanding L2 loads.
__global__ __launch_bounds__(256) void zq_kernel(const float* __restrict__ z,
                                                 const float* __restrict__ conv_w,
                                                 const float* __restrict__ conv_b,
                                                 const float* __restrict__ wq,
                                                 const float* __restrict__ bq,
                                                 const float* __restrict__ xmean,
                                                 float* __restrict__ znew,
                                                 float* __restrict__ qr) {
    int blk = blockIdx.x;
    int cgrp = blk & 7, bm = blk >> 3;
    int b = bm / NM, m = bm - b * NM;
    int tid = threadIdx.x;
    __shared__ float xm[NC];
    __shared__ float zn[ND];
    __shared__ float qpart[3][64];
    if (tid < NC) xm[tid] = xmean[(b * NC + tid) * NM + m];
    __syncthreads();
    if (tid < ND) {
        float a = conv_b[tid];
        const float4* wr4 = (const float4*)(conv_w + tid * NC);   // 256B-aligned
        #pragma unroll
        for (int c4 = 0; c4 < 16; ++c4) {
            float4 w = wr4[c4];
            a += w.x * xm[c4 * 4 + 0] + w.y * xm[c4 * 4 + 1]
               + w.z * xm[c4 * 4 + 2] + w.w * xm[c4 * 4 + 3];
        }
        float v = z[bm * ND + tid] + a;
        zn[tid] = v;
        if (cgrp == 0) znew[bm * ND + tid] = v;
    }
    __syncthreads();
    int colL = tid & 63, ks = tid >> 6;          // 64 cols x 4-way split-K(48)
    int col = cgrp * 64 + colL;
    float a = (ks == 0) ? bq[col] : 0.f;
    int d0 = ks * 48;
    #pragma unroll
    for (int d = d0; d < d0 + 48; ++d) a += zn[d] * wq[d * NINNER + col];
    if (ks > 0) qpart[ks - 1][colL] = a;
    __syncthreads();
    if (ks == 0) {
        float tot = a + qpart[0][colL] + qpart[1][colL] + qpart[2][colL];
        int t = m * 8 + cgrp;                    // permuted q layout [b][48][64]
        qr[b * (48 * 64) + t * 64 + colL] = tot;
    }
}

// ---------------- Kernel C: fattn (verbatim R4) ----------------
__global__ __launch_bounds__(256, 4) void fattn_kernel(const float* __restrict__ x,
                                                       const float* __restrict__ qr,
                                                       float* __restrict__ po,
                                                       float* __restrict__ ps) {
    int blk = blockIdx.x;
    int chunk = blk & 7, bh = blk >> 3;
    int head = bh & 7, b = bh >> 3;
    int tid = threadIdx.x;
    __shared__ float k_lds[CK][KP];
    __shared__ float q_lds[NM][KP];
    __shared__ float s_lds[NM][SP];
    __shared__ float pvp[3][NM][NCH];
    const float* kbase = x + (size_t)b * XB + (size_t)(head * NKEY + chunk * CK) * NCH;

    for (int i = tid; i < NM * NCH; i += 256) {
        int mi = i >> 6, ch = i & 63;
        q_lds[mi][ch] = qr[b * (48 * 64) + (head * NM + mi) * 64 + ch];
    }
    const float4* k4 = (const float4*)kbase;
    #pragma unroll
    for (int r = 0; r < 6; ++r) {
        int i = tid + r * 256;
        int row = i >> 4, c4 = i & 15;
        float4 v = k4[i];
        *(float4*)&k_lds[row][c4 * 4] = v;
    }
    __syncthreads();

    if (tid < 48) {
        int t = tid >> 1, mip = (tid & 1) * 3;
        float a[4][3];
        #pragma unroll
        for (int j = 0; j < 4; ++j) { a[j][0] = 0.f; a[j][1] = 0.f; a[j][2] = 0.f; }
        #pragma unroll 4
        for (int c = 0; c < 16; ++c) {
            float4 q0 = *(const float4*)&q_lds[mip + 0][c * 4];
            float4 q1 = *(const float4*)&q_lds[mip + 1][c * 4];
            float4 q2 = *(const float4*)&q_lds[mip + 2][c * 4];
            #pragma unroll
            for (int j = 0; j < 4; ++j) {
                float4 kv = *(const float4*)&k_lds[t + 24 * j][c * 4];
                a[j][0] += kv.x*q0.x + kv.y*q0.y + kv.z*q0.z + kv.w*q0.w;
                a[j][1] += kv.x*q1.x + kv.y*q1.y + kv.z*q1.z + kv.w*q1.w;
                a[j][2] += kv.x*q2.x + kv.y*q2.y + kv.z*q2.z + kv.w*q2.w;
            }
        }
        #pragma unroll
        for (int j = 0; j < 4; ++j) {
            s_lds[mip + 0][t + 24 * j] = __expf(a[j][0] * 0.125f);
            s_lds[mip + 1][t + 24 * j] = __expf(a[j][1] * 0.125f);
            s_lds[mip + 2][t + 24 * j] = __expf(a[j][2] * 0.125f);
        }
    }
    __syncthreads();

    int lane = tid & 63, wave = tid >> 6;
    #pragma unroll
    for (int rb = 0; rb < 2; ++rb) {
        int mi = rb * 4 + wave;
        if (mi < NM) {
            float v = s_lds[mi][lane] + ((lane < 32) ? s_lds[mi][64 + lane] : 0.f);
            for (int msk = 1; msk < 64; msk <<= 1) v += __shfl_xor(v, msk, 64);
            if (lane == 0) ps[blk * NM + mi] = v;
        }
    }

    float acc[NM] = {0.f,0.f,0.f,0.f,0.f,0.f};
    {
        int uq = tid >> 6, ch = tid & 63;
        int u0 = uq * 24;
        #pragma unroll
        for (int ub = 0; ub < 6; ++ub) {
            float4 s0 = *(const float4*)&s_lds[0][u0 + ub * 4];
            float4 s1 = *(const float4*)&s_lds[1][u0 + ub * 4];
            float4 s2 = *(const float4*)&s_lds[2][u0 + ub * 4];
            float4 s3 = *(const float4*)&s_lds[3][u0 + ub * 4];
            float4 s4 = *(const float4*)&s_lds[4][u0 + ub * 4];
            float4 s5 = *(const float4*)&s_lds[5][u0 + ub * 4];
            float kv0 = k_lds[u0 + ub * 4 + 0][ch];
            float kv1 = k_lds[u0 + ub * 4 + 1][ch];
            float kv2 = k_lds[u0 + ub * 4 + 2][ch];
            float kv3 = k_lds[u0 + ub * 4 + 3][ch];
            acc[0] += s0.x*kv0 + s0.y*kv1 + s0.z*kv2 + s0.w*kv3;
            acc[1] += s1.x*kv0 + s1.y*kv1 + s1.z*kv2 + s1.w*kv3;
            acc[2] += s2.x*kv0 + s2.y*kv1 + s2.z*kv2 + s2.w*kv3;
            acc[3] += s3.x*kv0 + s3.y*kv1 + s3.z*kv2 + s3.w*kv3;
            acc[4] += s4.x*kv0 + s4.y*kv1 + s4.z*kv2 + s4.w*kv3;
            acc[5] += s5.x*kv0 + s5.y*kv1 + s5.z*kv2 + s5.w*kv3;
        }
        if (uq > 0) {
            #pragma unroll
            for (int mo = 0; mo < NM; ++mo) pvp[uq - 1][mo][ch] = acc[mo];
        }
    }
    __syncthreads();
    if (tid < 64) {
        int ch = tid;
        #pragma unroll
        for (int mo = 0; mo < NM; ++mo) {
            float o = acc[mo] + pvp[0][mo][ch] + pvp[1][mo][ch] + pvp[2][mo][ch];
            po[(size_t)blk * (NM * NCH) + mo * NCH + ch] = o;
        }
    }
}

// ---------------- Kernel D: proj v2 — latency-chain diet ----------------
// grid = NB*NM*4 = 384 blocks, 256 threads (proven grid shape).
// po-combine: 128 threads x float4 (8 f4-loads + 8 broadcast ps loads each,
//   den folded per-thread -> no staging barrier).
// wo-dot: 16-way split-K of 32 (vs 4x128) with float4 wo loads
//   (12 col4-groups x 16 ks) -> 4 latency rounds instead of 16.
__global__ __launch_bounds__(256) void proj_kernel(const float* __restrict__ znew,
                                                   const float* __restrict__ po,
                                                   const float* __restrict__ ps,
                                                   const float* __restrict__ wo,
                                                   const float* __restrict__ bo,
                                                   float* __restrict__ out) {
    int blk = blockIdx.x;
    int cgrp = blk & 3, bm = blk >> 2;
    int b = bm / NM, m = bm - b * NM;
    int tid = threadIdx.x;
    __shared__ float4 orow4[128];            // 512 inner values
    __shared__ float4 part4[16][12];         // [ks][col4-group]

    // combine: thread t<128 handles inner [4t,4t+4) = head h = t>>4, ch4 = t&15
    if (tid < 128) {
        int h = tid >> 4, c16 = tid & 15;
        int base = (b * NHEADS + h) * NCHUNK;
        const float4* po4 = (const float4*)po;
        float4 n = make_float4(0.f, 0.f, 0.f, 0.f);
        float den = 0.f;
        #pragma unroll
        for (int c = 0; c < NCHUNK; ++c) {
            float4 v = po4[(size_t)(base + c) * 96 + m * 16 + c16];
            n.x += v.x; n.y += v.y; n.z += v.z; n.w += v.w;
            den += ps[(base + c) * NM + m];
        }
        float inv = 1.0f / den;
        n.x *= inv; n.y *= inv; n.z *= inv; n.w *= inv;
        orow4[tid] = n;
    }
    __syncthreads();

    // wo-dot: t<192: g4 = t%12 (4 cols), ks = t/12 (32 i's each)
    if (tid < 192) {
        int g4 = tid % 12, ks = tid / 12;
        int cb = cgrp * 12 + g4;             // float4 column-group index
        const float4* wo4 = (const float4*)wo;
        const float* orow = (const float*)orow4;
        float4 acc = make_float4(0.f, 0.f, 0.f, 0.f);
        int i0 = ks * 32;
        #pragma unroll 8
        for (int i = i0; i < i0 + 32; ++i) {
            float s = orow[i];
            float4 w = wo4[i * 48 + cb];
            acc.x += s * w.x; acc.y += s * w.y; acc.z += s * w.z; acc.w += s * w.w;
        }
        part4[ks][g4] = acc;
    }
    __syncthreads();

    // final: t<48 sums 16 partials + bias + residual
    if (tid < 48) {
        int g4 = tid >> 2, j = tid & 3;
        float s = 0.f;
        #pragma unroll
        for (int ks = 0; ks < 16; ++ks) s += ((const float*)&part4[ks][g4])[j];
        int col = cgrp * 48 + tid;
        out[bm * ND + col] = s + bo[col] + znew[bm * ND + col];
    }
}

extern "C" void kernel_launch(void* const* d_in, const int* in_sizes, int n_in,
                              void* d_out, int out_size, void* d_ws, size_t ws_size,
                              hipStream_t stream) {
    const float* x      = (const float*)d_in[0];
    const float* z      = (const float*)d_in[1];
    const float* conv_w = (const float*)d_in[2];
    const float* conv_b = (const float*)d_in[3];
    const float* wq     = (const float*)d_in[4];
    const float* bq     = (const float*)d_in[5];
    const float* wo     = (const float*)d_in[6];
    const float* bo     = (const float*)d_in[7];
    float* out = (float*)d_out;

    float* ws    = (float*)d_ws;
    float* xmean = ws;              // 16*64*6          = 6144
    float* znew  = ws + 6144;       // 16*6*192         = 18432
    float* qr    = ws + 24576;      // 16*48*64         = 49152
    float* po    = ws + 73728;      // 1024*6*64        = 393216
    float* ps    = ws + 466944;     // 1024*6           = 6144

    pool_kernel<<<NB*NC, 256, 0, stream>>>(x, xmean);
    zq_kernel<<<NB*NM*8, 256, 0, stream>>>(z, conv_w, conv_b, wq, bq, xmean, znew, qr);
    fattn_kernel<<<NB*NHEADS*NCHUNK, 256, 0, stream>>>(x, qr, po, ps);
    proj_kernel<<<NB*NM*4, 256, 0, stream>>>(znew, po, ps, wo, bo, out);
}

// Round 11
// 32.123 us; speedup vs baseline: 12.5134x; 1.0047x over previous
//
#include <hip/hip_runtime.h>

// Problem constants
#define NB 16
#define NC 64
#define NM 6
#define ND 192
#define NHEADS 8
#define NCH 64
#define NINNER 512
#define PLANE 6144             // 64*96 floats per (b,c) plane
#define XB (NC*PLANE)          // 393216 floats of x per batch
#define NKEY 768               // unique keys per head (dup-8 collapses in softmax)
#define NCHUNK 8
#define CK 96                  // keys per chunk (8*96 = 768)
#define KP 68                  // k/q row pitch (272B, 16B-aligned)
#define SP 100                 // s row pitch

// ---------------- Kernel A: pool (verbatim R10) ----------------
__global__ __launch_bounds__(256) void pool_kernel(const float* __restrict__ x,
                                                   float* __restrict__ xmean) {
    int bc = blockIdx.x;
    const float4* p = (const float4*)(x + (size_t)bc * PLANE);
    int tid = threadIdx.x;
    float acc[6] = {0.f,0.f,0.f,0.f,0.f,0.f};
    #pragma unroll
    for (int k = 0; k < 6; ++k) {
        int idx4 = tid + k * 256;
        int hh = idx4 / 24;
        int w4 = idx4 - hh * 24;
        int j = (hh >> 5) * 3 + (w4 >> 3);
        float4 v = p[idx4];
        acc[j] += v.x + v.y + v.z + v.w;
    }
    int lane = tid & 63, wave = tid >> 6;
    #pragma unroll
    for (int j = 0; j < 6; ++j) {
        float v = acc[j];
        for (int off = 32; off > 0; off >>= 1) v += __shfl_down(v, off, 64);
        acc[j] = v;
    }
    __shared__ float part[4][6];
    if (lane == 0) {
        #pragma unroll
        for (int j = 0; j < 6; ++j) part[wave][j] = acc[j];
    }
    __syncthreads();
    if (tid < 6) {
        float s = part[0][tid] + part[1][tid] + part[2][tid] + part[3][tid];
        xmean[bc * 6 + tid] = s * (1.0f / 1024.0f);
    }
}

// ---------------- Kernel B: zq (verbatim R10) ----------------
__global__ __launch_bounds__(256) void zq_kernel(const float* __restrict__ z,
                                                 const float* __restrict__ conv_w,
                                                 const float* __restrict__ conv_b,
                                                 const float* __restrict__ wq,
                                                 const float* __restrict__ bq,
                                                 const float* __restrict__ xmean,
                                                 float* __restrict__ znew,
                                                 float* __restrict__ qr) {
    int blk = blockIdx.x;
    int cgrp = blk & 7, bm = blk >> 3;
    int b = bm / NM, m = bm - b * NM;
    int tid = threadIdx.x;
    __shared__ float xm[NC];
    __shared__ float zn[ND];
    __shared__ float qpart[3][64];
    if (tid < NC) xm[tid] = xmean[(b * NC + tid) * NM + m];
    __syncthreads();
    if (tid < ND) {
        float a = conv_b[tid];
        const float4* wr4 = (const float4*)(conv_w + tid * NC);
        #pragma unroll
        for (int c4 = 0; c4 < 16; ++c4) {
            float4 w = wr4[c4];
            a += w.x * xm[c4 * 4 + 0] + w.y * xm[c4 * 4 + 1]
               + w.z * xm[c4 * 4 + 2] + w.w * xm[c4 * 4 + 3];
        }
        float v = z[bm * ND + tid] + a;
        zn[tid] = v;
        if (cgrp == 0) znew[bm * ND + tid] = v;
    }
    __syncthreads();
    int colL = tid & 63, ks = tid >> 6;
    int col = cgrp * 64 + colL;
    float a = (ks == 0) ? bq[col] : 0.f;
    int d0 = ks * 48;
    #pragma unroll
    for (int d = d0; d < d0 + 48; ++d) a += zn[d] * wq[d * NINNER + col];
    if (ks > 0) qpart[ks - 1][colL] = a;
    __syncthreads();
    if (ks == 0) {
        float tot = a + qpart[0][colL] + qpart[1][colL] + qpart[2][colL];
        int t = m * 8 + cgrp;
        qr[b * (48 * 64) + t * 64 + colL] = tot;
    }
}

// ---------------- Kernel C: fattn v4 — LDS-instruction diet ----------------
// grid = NB*NHEADS*NCHUNK = 1024 blocks, 256 threads, 4 blocks/CU.
// dots: 96 threads (one per k-row), all 6 m per thread; q reads are
//   wave-uniform broadcasts; k b128 reads uniform-8-way (minimum).
// PV: 256 threads = 16 col-quads x 16 row-groups(6). Per thread:
//   6 b128 k-reads + 36 broadcast s-reads + 144 FMA (was 144 b32 + 36 b128).
//   In-wave shfl_xor(16/32) folds 4 row-groups -> pvp4[4][6][16] (6KB).
__global__ __launch_bounds__(256, 4) void fattn_kernel(const float* __restrict__ x,
                                                       const float* __restrict__ qr,
                                                       float* __restrict__ po,
                                                       float* __restrict__ ps) {
    int blk = blockIdx.x;                    // ((b*8+head)*8+chunk)
    int chunk = blk & 7, bh = blk >> 3;
    int head = bh & 7, b = bh >> 3;
    int tid = threadIdx.x;
    __shared__ float k_lds[CK][KP];          // 26112 B
    __shared__ float q_lds[NM][KP];          //  1632 B
    __shared__ float s_lds[NM][SP];          //  2400 B
    __shared__ float4 pvp4[4][NM][16];       //  6144 B  (total 36288 B)
    const float* kbase = x + (size_t)b * XB + (size_t)(head * NKEY + chunk * CK) * NCH;

    // q load (coalesced; qr pre-permuted)
    for (int i = tid; i < NM * NCH; i += 256) {
        int mi = i >> 6, ch = i & 63;
        q_lds[mi][ch] = qr[b * (48 * 64) + (head * NM + mi) * 64 + ch];
    }
    // k tile: 96 rows x 16 float4, aligned float4 LDS writes
    const float4* k4 = (const float4*)kbase;
    #pragma unroll
    for (int r = 0; r < 6; ++r) {
        int i = tid + r * 256;
        int row = i >> 4, c4 = i & 15;
        float4 v = k4[i];
        *(float4*)&k_lds[row][c4 * 4] = v;
    }
    __syncthreads();

    // ---- dots + exp: 96 threads, thread = k-row u, all 6 m ----
    if (tid < 96) {
        int u = tid;
        float a[NM] = {0.f,0.f,0.f,0.f,0.f,0.f};
        #pragma unroll
        for (int c4 = 0; c4 < 16; ++c4) {
            float4 kv = *(const float4*)&k_lds[u][c4 * 4];
            #pragma unroll
            for (int mo = 0; mo < NM; ++mo) {
                float4 qv = *(const float4*)&q_lds[mo][c4 * 4];   // broadcast
                a[mo] += kv.x*qv.x + kv.y*qv.y + kv.z*qv.z + kv.w*qv.w;
            }
        }
        #pragma unroll
        for (int mo = 0; mo < NM; ++mo) s_lds[mo][u] = __expf(a[mo] * 0.125f);
    }
    __syncthreads();

    int lane = tid & 63, wave = tid >> 6;

    // ---- denominators -> ps (6 rows of 96; waves 0-3 then 0-1) ----
    #pragma unroll
    for (int rb = 0; rb < 2; ++rb) {
        int mi = rb * 4 + wave;
        if (mi < NM) {
            float v = s_lds[mi][lane] + ((lane < 32) ? s_lds[mi][64 + lane] : 0.f);
            for (int msk = 1; msk < 64; msk <<= 1) v += __shfl_xor(v, msk, 64);
            if (lane == 0) ps[blk * NM + mi] = v;
        }
    }

    // ---- PV: thread = (qd = tid&15 col-quad, rg = tid>>4 row-group of 6) --
    {
        int qd = tid & 15, rg = tid >> 4;
        float4 acc4[NM];
        #pragma unroll
        for (int mo = 0; mo < NM; ++mo) acc4[mo] = make_float4(0.f,0.f,0.f,0.f);
        int u0 = rg * 6;
        #pragma unroll
        for (int j = 0; j < 6; ++j) {
            int u = u0 + j;
            float4 kv = *(const float4*)&k_lds[u][qd * 4];
            #pragma unroll
            for (int mo = 0; mo < NM; ++mo) {
                float s = s_lds[mo][u];                           // broadcast
                acc4[mo].x += s * kv.x; acc4[mo].y += s * kv.y;
                acc4[mo].z += s * kv.z; acc4[mo].w += s * kv.w;
            }
        }
        // fold the wave's 4 row-groups (lane^16 flips rg bit0, lane^32 bit1)
        #pragma unroll
        for (int mo = 0; mo < NM; ++mo) {
            acc4[mo].x += __shfl_xor(acc4[mo].x, 16, 64);
            acc4[mo].y += __shfl_xor(acc4[mo].y, 16, 64);
            acc4[mo].z += __shfl_xor(acc4[mo].z, 16, 64);
            acc4[mo].w += __shfl_xor(acc4[mo].w, 16, 64);
            acc4[mo].x += __shfl_xor(acc4[mo].x, 32, 64);
            acc4[mo].y += __shfl_xor(acc4[mo].y, 32, 64);
            acc4[mo].z += __shfl_xor(acc4[mo].z, 32, 64);
            acc4[mo].w += __shfl_xor(acc4[mo].w, 32, 64);
        }
        if (lane < 16) {
            #pragma unroll
            for (int mo = 0; mo < NM; ++mo) pvp4[wave][mo][qd] = acc4[mo];
        }
    }
    __syncthreads();

    // ---- final: 96 threads (mo = tid>>4, qd = tid&15) sum 4 wave partials --
    if (tid < 96) {
        int mo = tid >> 4, qd = tid & 15;
        float4 o = pvp4[0][mo][qd];
        float4 o1 = pvp4[1][mo][qd];
        float4 o2 = pvp4[2][mo][qd];
        float4 o3 = pvp4[3][mo][qd];
        o.x += o1.x + o2.x + o3.x;
        o.y += o1.y + o2.y + o3.y;
        o.z += o1.z + o2.z + o3.z;
        o.w += o1.w + o2.w + o3.w;
        *(float4*)&po[(size_t)blk * (NM * NCH) + mo * NCH + qd * 4] = o;
    }
}

// ---------------- Kernel D: proj (verbatim R10) ----------------
__global__ __launch_bounds__(256) void proj_kernel(const float* __restrict__ znew,
                                                   const float* __restrict__ po,
                                                   const float* __restrict__ ps,
                                                   const float* __restrict__ wo,
                                                   const float* __restrict__ bo,
                                                   float* __restrict__ out) {
    int blk = blockIdx.x;
    int cgrp = blk & 3, bm = blk >> 2;
    int b = bm / NM, m = bm - b * NM;
    int tid = threadIdx.x;
    __shared__ float4 orow4[128];
    __shared__ float4 part4[16][12];

    if (tid < 128) {
        int h = tid >> 4, c16 = tid & 15;
        int base = (b * NHEADS + h) * NCHUNK;
        const float4* po4 = (const float4*)po;
        float4 n = make_float4(0.f, 0.f, 0.f, 0.f);
        float den = 0.f;
        #pragma unroll
        for (int c = 0; c < NCHUNK; ++c) {
            float4 v = po4[(size_t)(base + c) * 96 + m * 16 + c16];
            n.x += v.x; n.y += v.y; n.z += v.z; n.w += v.w;
            den += ps[(base + c) * NM + m];
        }
        float inv = 1.0f / den;
        n.x *= inv; n.y *= inv; n.z *= inv; n.w *= inv;
        orow4[tid] = n;
    }
    __syncthreads();

    if (tid < 192) {
        int g4 = tid % 12, ks = tid / 12;
        int cb = cgrp * 12 + g4;
        const float4* wo4 = (const float4*)wo;
        const float* orow = (const float*)orow4;
        float4 acc = make_float4(0.f, 0.f, 0.f, 0.f);
        int i0 = ks * 32;
        #pragma unroll 8
        for (int i = i0; i < i0 + 32; ++i) {
            float s = orow[i];
            float4 w = wo4[i * 48 + cb];
            acc.x += s * w.x; acc.y += s * w.y; acc.z += s * w.z; acc.w += s * w.w;
        }
        part4[ks][g4] = acc;
    }
    __syncthreads();

    if (tid < 48) {
        int g4 = tid >> 2, j = tid & 3;
        float s = 0.f;
        #pragma unroll
        for (int ks = 0; ks < 16; ++ks) s += ((const float*)&part4[ks][g4])[j];
        int col = cgrp * 48 + tid;
        out[bm * ND + col] = s + bo[col] + znew[bm * ND + col];
    }
}

extern "C" void kernel_launch(void* const* d_in, const int* in_sizes, int n_in,
                              void* d_out, int out_size, void* d_ws, size_t ws_size,
                              hipStream_t stream) {
    const float* x      = (const float*)d_in[0];
    const float* z      = (const float*)d_in[1];
    const float* conv_w = (const float*)d_in[2];
    const float* conv_b = (const float*)d_in[3];
    const float* wq     = (const float*)d_in[4];
    const float* bq     = (const float*)d_in[5];
    const float* wo     = (const float*)d_in[6];
    const float* bo     = (const float*)d_in[7];
    float* out = (float*)d_out;

    float* ws    = (float*)d_ws;
    float* xmean = ws;              // 16*64*6          = 6144
    float* znew  = ws + 6144;       // 16*6*192         = 18432
    float* qr    = ws + 24576;      // 16*48*64         = 49152
    float* po    = ws + 73728;      // 1024*6*64        = 393216
    float* ps    = ws + 466944;     // 1024*6           = 6144

    pool_kernel<<<NB*NC, 256, 0, stream>>>(x, xmean);
    zq_kernel<<<NB*NM*8, 256, 0, stream>>>(z, conv_w, conv_b, wq, bq, xmean, znew, qr);
    fattn_kernel<<<NB*NHEADS*NCHUNK, 256, 0, stream>>>(x, qr, po, ps);
    proj_kernel<<<NB*NM*4, 256, 0, stream>>>(znew, po, ps, wo, bo, out);
}

// Round 12
// 31.612 us; speedup vs baseline: 12.7159x; 1.0162x over previous
//
#include <hip/hip_runtime.h>

// Problem constants
#define NB 16
#define NC 64
#define NM 6
#define ND 192
#define NHEADS 8
#define NCH 64
#define NINNER 512
#define PLANE 6144             // 64*96 floats per (b,c) plane
#define XB (NC*PLANE)          // 393216 floats of x per batch
#define NKEY 768               // unique keys per head (dup-8 collapses in softmax)
#define NCHUNK 8
#define CK 96                  // keys per chunk (8*96 = 768)

// ---------------- Kernel A: pool (verbatim R10) ----------------
__global__ __launch_bounds__(256) void pool_kernel(const float* __restrict__ x,
                                                   float* __restrict__ xmean) {
    int bc = blockIdx.x;
    const float4* p = (const float4*)(x + (size_t)bc * PLANE);
    int tid = threadIdx.x;
    float acc[6] = {0.f,0.f,0.f,0.f,0.f,0.f};
    #pragma unroll
    for (int k = 0; k < 6; ++k) {
        int idx4 = tid + k * 256;
        int hh = idx4 / 24;
        int w4 = idx4 - hh * 24;
        int j = (hh >> 5) * 3 + (w4 >> 3);
        float4 v = p[idx4];
        acc[j] += v.x + v.y + v.z + v.w;
    }
    int lane = tid & 63, wave = tid >> 6;
    #pragma unroll
    for (int j = 0; j < 6; ++j) {
        float v = acc[j];
        for (int off = 32; off > 0; off >>= 1) v += __shfl_down(v, off, 64);
        acc[j] = v;
    }
    __shared__ float part[4][6];
    if (lane == 0) {
        #pragma unroll
        for (int j = 0; j < 6; ++j) part[wave][j] = acc[j];
    }
    __syncthreads();
    if (tid < 6) {
        float s = part[0][tid] + part[1][tid] + part[2][tid] + part[3][tid];
        xmean[bc * 6 + tid] = s * (1.0f / 1024.0f);
    }
}

// ---------------- Kernel B: zq (verbatim R10) ----------------
__global__ __launch_bounds__(256) void zq_kernel(const float* __restrict__ z,
                                                 const float* __restrict__ conv_w,
                                                 const float* __restrict__ conv_b,
                                                 const float* __restrict__ wq,
                                                 const float* __restrict__ bq,
                                                 const float* __restrict__ xmean,
                                                 float* __restrict__ znew,
                                                 float* __restrict__ qr) {
    int blk = blockIdx.x;
    int cgrp = blk & 7, bm = blk >> 3;
    int b = bm / NM, m = bm - b * NM;
    int tid = threadIdx.x;
    __shared__ float xm[NC];
    __shared__ float zn[ND];
    __shared__ float qpart[3][64];
    if (tid < NC) xm[tid] = xmean[(b * NC + tid) * NM + m];
    __syncthreads();
    if (tid < ND) {
        float a = conv_b[tid];
        const float4* wr4 = (const float4*)(conv_w + tid * NC);
        #pragma unroll
        for (int c4 = 0; c4 < 16; ++c4) {
            float4 w = wr4[c4];
            a += w.x * xm[c4 * 4 + 0] + w.y * xm[c4 * 4 + 1]
               + w.z * xm[c4 * 4 + 2] + w.w * xm[c4 * 4 + 3];
        }
        float v = z[bm * ND + tid] + a;
        zn[tid] = v;
        if (cgrp == 0) znew[bm * ND + tid] = v;
    }
    __syncthreads();
    int colL = tid & 63, ks = tid >> 6;
    int col = cgrp * 64 + colL;
    float a = (ks == 0) ? bq[col] : 0.f;
    int d0 = ks * 48;
    #pragma unroll
    for (int d = d0; d < d0 + 48; ++d) a += zn[d] * wq[d * NINNER + col];
    if (ks > 0) qpart[ks - 1][colL] = a;
    __syncthreads();
    if (ks == 0) {
        float tot = a + qpart[0][colL] + qpart[1][colL] + qpart[2][colL];
        int t = m * 8 + cgrp;
        qr[b * (48 * 64) + t * 64 + colL] = tot;
    }
}

// ---------------- Kernel C: fattn v5 — occupancy (5 blocks/CU) ------------
// grid = 1024 blocks, 256 threads. LDS 28416B < 32K -> 5 blocks/CU (20 waves
// vs 16): +25% TLP to hide staging/L3 latency (R9: VALUBusy 55%, occ 42%).
// Phases: stage -> B1 -> dots(96thr, rotated c4) -> B2 ->
//         {waves 0-1: PV direct-write (no pvp, no combine), waves 2-3: den}.
// Bank audit: staging/dots b128 at wave64 structural 8-way min; PV k-reads
// bank=ch%32 2-way (free, m136); s reads broadcast.
__global__ __launch_bounds__(256, 5) void fattn_kernel(const float* __restrict__ x,
                                                       const float* __restrict__ qr,
                                                       float* __restrict__ po,
                                                       float* __restrict__ ps) {
    int blk = blockIdx.x;                    // ((b*8+head)*8+chunk)
    int chunk = blk & 7, bh = blk >> 3;
    int head = bh & 7, b = bh >> 3;
    int tid = threadIdx.x;
    __shared__ float k_lds[CK][NCH];         // 24576 B (pitch 64)
    __shared__ float q_lds[NM][NCH];         //  1536 B
    __shared__ float s_lds[NM][CK];          //  2304 B   (total 28416 B)
    const float* kbase = x + (size_t)b * XB + (size_t)(head * NKEY + chunk * CK) * NCH;

    // q load (coalesced; qr pre-permuted)
    for (int i = tid; i < NM * NCH; i += 256) {
        int mi = i >> 6, ch = i & 63;
        q_lds[mi][ch] = qr[b * (48 * 64) + (head * NM + mi) * 64 + ch];
    }
    // k tile: 96 rows x 16 float4 (aligned b128 writes, 8-way = b128 minimum)
    const float4* k4 = (const float4*)kbase;
    #pragma unroll
    for (int r = 0; r < 6; ++r) {
        int i = tid + r * 256;
        int row = i >> 4, c4 = i & 15;
        float4 v = k4[i];
        *(float4*)&k_lds[row][c4 * 4] = v;
    }
    __syncthreads();

    // ---- dots + exp: 96 threads, thread = k-row u, all 6 m.
    // Per-thread rotation c4' = (c4+u)&15 avoids all-lanes-same-bank-group.
    if (tid < 96) {
        int u = tid;
        float a[NM] = {0.f,0.f,0.f,0.f,0.f,0.f};
        #pragma unroll
        for (int c4 = 0; c4 < 16; ++c4) {
            int cc = ((c4 + u) & 15) * 4;
            float4 kv = *(const float4*)&k_lds[u][cc];
            #pragma unroll
            for (int mo = 0; mo < NM; ++mo) {
                float4 qv = *(const float4*)&q_lds[mo][cc];     // broadcast
                a[mo] += kv.x*qv.x + kv.y*qv.y + kv.z*qv.z + kv.w*qv.w;
            }
        }
        #pragma unroll
        for (int mo = 0; mo < NM; ++mo) s_lds[mo][u] = __expf(a[mo] * 0.125f);
    }
    __syncthreads();

    int lane = tid & 63, wave = tid >> 6;

    if (wave < 2) {
        // ---- PV: thread (ch = tid&63, trio = wave) walks ALL 96 rows.
        // k scalar reads bank=ch%32 (2-way, free); s float4 broadcasts.
        int ch = lane, m0 = wave * 3;
        float a0 = 0.f, a1 = 0.f, a2 = 0.f;
        #pragma unroll
        for (int u0 = 0; u0 < CK; u0 += 4) {
            float4 s0 = *(const float4*)&s_lds[m0 + 0][u0];
            float4 s1 = *(const float4*)&s_lds[m0 + 1][u0];
            float4 s2 = *(const float4*)&s_lds[m0 + 2][u0];
            float kv0 = k_lds[u0 + 0][ch];
            float kv1 = k_lds[u0 + 1][ch];
            float kv2 = k_lds[u0 + 2][ch];
            float kv3 = k_lds[u0 + 3][ch];
            a0 += s0.x*kv0 + s0.y*kv1 + s0.z*kv2 + s0.w*kv3;
            a1 += s1.x*kv0 + s1.y*kv1 + s1.z*kv2 + s1.w*kv3;
            a2 += s2.x*kv0 + s2.y*kv1 + s2.z*kv2 + s2.w*kv3;
        }
        float* pob = po + (size_t)blk * (NM * NCH);
        pob[(m0 + 0) * NCH + ch] = a0;
        pob[(m0 + 1) * NCH + ch] = a1;
        pob[(m0 + 2) * NCH + ch] = a2;
    } else {
        // ---- denominators: waves 2-3 cover 6 rows in 3 rounds.
        #pragma unroll
        for (int rnd = 0; rnd < 3; ++rnd) {
            int mi = rnd * 2 + (wave - 2);
            float v = s_lds[mi][lane] + ((lane < 32) ? s_lds[mi][64 + lane] : 0.f);
            for (int msk = 1; msk < 64; msk <<= 1) v += __shfl_xor(v, msk, 64);
            if (lane == 0) ps[blk * NM + mi] = v;
        }
    }
}

// ---------------- Kernel D: proj (verbatim R10) ----------------
__global__ __launch_bounds__(256) void proj_kernel(const float* __restrict__ znew,
                                                   const float* __restrict__ po,
                                                   const float* __restrict__ ps,
                                                   const float* __restrict__ wo,
                                                   const float* __restrict__ bo,
                                                   float* __restrict__ out) {
    int blk = blockIdx.x;
    int cgrp = blk & 3, bm = blk >> 2;
    int b = bm / NM, m = bm - b * NM;
    int tid = threadIdx.x;
    __shared__ float4 orow4[128];
    __shared__ float4 part4[16][12];

    if (tid < 128) {
        int h = tid >> 4, c16 = tid & 15;
        int base = (b * NHEADS + h) * NCHUNK;
        const float4* po4 = (const float4*)po;
        float4 n = make_float4(0.f, 0.f, 0.f, 0.f);
        float den = 0.f;
        #pragma unroll
        for (int c = 0; c < NCHUNK; ++c) {
            float4 v = po4[(size_t)(base + c) * 96 + m * 16 + c16];
            n.x += v.x; n.y += v.y; n.z += v.z; n.w += v.w;
            den += ps[(base + c) * NM + m];
        }
        float inv = 1.0f / den;
        n.x *= inv; n.y *= inv; n.z *= inv; n.w *= inv;
        orow4[tid] = n;
    }
    __syncthreads();

    if (tid < 192) {
        int g4 = tid % 12, ks = tid / 12;
        int cb = cgrp * 12 + g4;
        const float4* wo4 = (const float4*)wo;
        const float* orow = (const float*)orow4;
        float4 acc = make_float4(0.f, 0.f, 0.f, 0.f);
        int i0 = ks * 32;
        #pragma unroll 8
        for (int i = i0; i < i0 + 32; ++i) {
            float s = orow[i];
            float4 w = wo4[i * 48 + cb];
            acc.x += s * w.x; acc.y += s * w.y; acc.z += s * w.z; acc.w += s * w.w;
        }
        part4[ks][g4] = acc;
    }
    __syncthreads();

    if (tid < 48) {
        int g4 = tid >> 2, j = tid & 3;
        float s = 0.f;
        #pragma unroll
        for (int ks = 0; ks < 16; ++ks) s += ((const float*)&part4[ks][g4])[j];
        int col = cgrp * 48 + tid;
        out[bm * ND + col] = s + bo[col] + znew[bm * ND + col];
    }
}

extern "C" void kernel_launch(void* const* d_in, const int* in_sizes, int n_in,
                              void* d_out, int out_size, void* d_ws, size_t ws_size,
                              hipStream_t stream) {
    const float* x      = (const float*)d_in[0];
    const float* z      = (const float*)d_in[1];
    const float* conv_w = (const float*)d_in[2];
    const float* conv_b = (const float*)d_in[3];
    const float* wq     = (const float*)d_in[4];
    const float* bq     = (const float*)d_in[5];
    const float* wo     = (const float*)d_in[6];
    const float* bo     = (const float*)d_in[7];
    float* out = (float*)d_out;

    float* ws    = (float*)d_ws;
    float* xmean = ws;              // 16*64*6          = 6144
    float* znew  = ws + 6144;       // 16*6*192         = 18432
    float* qr    = ws + 24576;      // 16*48*64         = 49152
    float* po    = ws + 73728;      // 1024*6*64        = 393216
    float* ps    = ws + 466944;     // 1024*6           = 6144

    pool_kernel<<<NB*NC, 256, 0, stream>>>(x, xmean);
    zq_kernel<<<NB*NM*8, 256, 0, stream>>>(z, conv_w, conv_b, wq, bq, xmean, znew, qr);
    fattn_kernel<<<NB*NHEADS*NCHUNK, 256, 0, stream>>>(x, qr, po, ps);
    proj_kernel<<<NB*NM*4, 256, 0, stream>>>(znew, po, ps, wo, bo, out);
}